// Round 8
// baseline (22.331 us; speedup 1.0000x reference)
//
#include <hip/hip_runtime.h>

// B=131072, S=4, D=128, H=1
//   u[b] = dot(x[b,0,:], w) + bias     (reads only first S-slice: 64 MB)
//   y[b] = u[b] + a*y[b-1],  a = weight_h[0,0]
// SINGLE kernel at FULL occupancy: 2048 blocks (= residency capacity,
// launch_bounds(256,8) pins VGPR<=64), chunk=64 rows/block. Dot identical to
// the round-6 K1. Wave 0 scans + publishes aggregate while waves 1-3 poll
// lookback windows. No u round-trip, no second dispatch.

#define B_ROWS 131072
#define CHUNK  64
#define NCHUNK 2048  // B_ROWS / CHUNK == exactly the 8-blocks/CU capacity
#define MAGIC  0x7C3A9E51u

template <int CTRL>
__device__ __forceinline__ float dpp_add(float s) {
    int v = __builtin_amdgcn_update_dpp(0, __builtin_bit_cast(int, s), CTRL, 0xF, 0xF, true);
    return s + __builtin_bit_cast(float, v);
}

__global__ __launch_bounds__(256, 8) void k_fused(const float* __restrict__ x,
                                                  const float* __restrict__ w,
                                                  const float* __restrict__ wh_p,
                                                  const float* __restrict__ bias,
                                                  float* __restrict__ out,
                                                  unsigned long long* __restrict__ pk) {
    __shared__ float u_s[CHUNK];
    __shared__ float Sw[32];            // per-window weighted sums (nw <= 32)
    __shared__ float ex_s;
    const int tid  = threadIdx.x;
    const int wv   = tid >> 6;          // wave 0..3
    const int lane = tid & 63;
    const int half = lane >> 5;         // which row of the pair
    const int hl   = lane & 31;         // lane within half-wave
    const int k    = blockIdx.x;        // chunk id
    const int base = k * CHUNK;

    const float4 wvec = *reinterpret_cast<const float4*>(w + hl * 4);
    const float  bs   = bias[0];
    // wave wv owns rows [base + wv*16, base + wv*16 + 16): 8 iters x 2 rows
    const float* xp = x + (size_t)(base + wv * 16 + half) * 512 + hl * 4;

    // ---- dot: hoist all 8 loads (8 KB/wave in flight), then DPP reduce ----
    float4 xv[8];
#pragma unroll
    for (int r = 0; r < 8; ++r)
        xv[r] = *reinterpret_cast<const float4*>(xp + (size_t)r * 1024);
#pragma unroll
    for (int r = 0; r < 8; ++r) {
        float s = fmaf(xv[r].x, wvec.x, fmaf(xv[r].y, wvec.y,
                  fmaf(xv[r].z, wvec.z, xv[r].w * wvec.w)));
        s = dpp_add<0xB1>(s);    // xor1 (quad_perm)
        s = dpp_add<0x4E>(s);    // xor2 (quad_perm)
        s = dpp_add<0x141>(s);   // row_half_mirror
        s = dpp_add<0x140>(s);   // row_mirror
        s += __shfl_xor(s, 16, 64);
        if (hl == 0) u_s[wv * 16 + r * 2 + half] = s + bs;
    }
    __syncthreads();

    // Af = a^CHUNK = a^64 (all threads need it for window math)
    const float a = wh_p[0];
    float Af = a;
#pragma unroll
    for (int b = 0; b < 6; ++b) Af *= Af;

    // ---- wave 0: 64-wide weighted scan of u_s, publish aggregate ASAP ----
    float c = 0.0f;
    if (wv == 0) {
        c = u_s[lane];
        float f = a;
#pragma unroll
        for (int s = 1; s < 64; s <<= 1) {
            float prev = __shfl_up(c, (unsigned)s, 64);
            if (lane >= s) c = fmaf(prev, f, c);
            f *= f;
        }
        if (lane == 63) {               // lane 63 holds the chunk aggregate
            unsigned long long q =
                ((unsigned long long)__float_as_uint(c) << 32) | (unsigned long long)MAGIC;
            __hip_atomic_store(&pk[k], q, __ATOMIC_RELAXED, __HIP_MEMORY_SCOPE_AGENT);
        }
    }

    // ---- lookback: nw windows of 64 predecessors, 4-way wave-parallel ----
    // (waves 1-3 start polling immediately; wave 0 joins after its scan)
    const int nw = (k + 63) >> 6;
    for (int wi = wv; wi < nw; wi += 4) {
        const int j0 = wi << 6;
        const int t  = min(64, k - j0);     // chunks in this window, 1..64
        float cj = 0.0f;
        if (lane < t) {
            unsigned long long q = __hip_atomic_load(&pk[j0 + lane], __ATOMIC_RELAXED,
                                                     __HIP_MEMORY_SCOPE_AGENT);
            while ((unsigned int)q != MAGIC) {
                __builtin_amdgcn_s_sleep(1);
                q = __hip_atomic_load(&pk[j0 + lane], __ATOMIC_RELAXED,
                                      __HIP_MEMORY_SCOPE_AGENT);
            }
            cj = __uint_as_float((unsigned int)(q >> 32));
        }
        float P = cj, ff = Af;              // weighted scan; lane t-1 = window sum
#pragma unroll
        for (int s = 1; s < 64; s <<= 1) {
            float prev = __shfl_up(P, (unsigned)s, 64);
            if (lane >= s) P = fmaf(prev, ff, P);
            ff *= ff;
        }
        if (lane == t - 1) Sw[wi] = P;
    }
    __syncthreads();

    // ---- combine windows (Horner, fixed order -> deterministic) ----
    if (tid == 0) {
        float ex = 0.0f;
        if (nw > 0) {
            float A64 = Af;
#pragma unroll
            for (int i = 0; i < 6; ++i) A64 *= A64;       // Af^64
            for (int wi = 0; wi < nw - 1; ++wi) ex = fmaf(ex, A64, Sw[wi]);
            const int tl = k - ((nw - 1) << 6);           // last-window len 1..64
            float At = 1.0f, bb = Af;
#pragma unroll
            for (int b = 0; b < 7; ++b) { if (tl & (1 << b)) At *= bb; bb *= bb; }
            ex = fmaf(ex, At, Sw[nw - 1]);
        }
        ex_s = ex;
    }
    __syncthreads();

    // ---- wave 0: y_i = p_i + a^(lane+1) * ex ; 256B coalesced store ----
    if (wv == 0) {
        const float ex = ex_s;
        float apw = a, bse = a;             // a^(lane+1)
#pragma unroll
        for (int b = 0; b < 6; ++b) { if (lane & (1 << b)) apw *= bse; bse *= bse; }
        const float y = fmaf(apw, ex, c);
        out[base + lane] = y;
        if (k == NCHUNK - 1 && lane == 63) {   // y_h duplicated tail
            out[B_ROWS]     = y;
            out[B_ROWS + 1] = y;
        }
    }
}

extern "C" void kernel_launch(void* const* d_in, const int* in_sizes, int n_in,
                              void* d_out, int out_size, void* d_ws, size_t ws_size,
                              hipStream_t stream) {
    const float* x    = (const float*)d_in[0];   // (131072, 4, 128) f32
    const float* w    = (const float*)d_in[1];   // (128, 1) f32
    const float* wh   = (const float*)d_in[2];   // (1, 1) f32
    const float* bias = (const float*)d_in[3];   // (1,) f32
    float* out = (float*)d_out;                  // 131074 f32

    unsigned long long* pk = (unsigned long long*)d_ws;  // NCHUNK qwords

    k_fused<<<NCHUNK, 256, 0, stream>>>(x, w, wh, bias, out, pk);
}

// Round 9
// 20.233 us; speedup vs baseline: 1.1037x; 1.1037x over previous
//
#include <hip/hip_runtime.h>

// B=131072, S=4, D=128, H=1
//   u[b] = dot(x[b,0,:], w) + bias     (reads only first S-slice: 64 MB)
//   y[b] = u[b] + a*y[b-1],  a = weight_h[0,0]
// ONE dispatch, 2560 blocks: 2048 producer blocks stream the dot at full
// occupancy and publish u as {value,MAGIC} qwords (relaxed agent atomics,
// value carried with flag -> no fences); 512 consumer blocks poll their
// chunk's u, scan, decoupled-lookback, and write out — overlapped with the
// stream tail. Deadlock-free for any dispatch order (producers never wait).

#define B_ROWS 131072
#define CHUNK  256
#define NCHUNK 512   // B_ROWS / CHUNK
#define NDOT   2048  // producer blocks
#define MAGIC  0x7C3A9E51u

template <int CTRL>
__device__ __forceinline__ float dpp_add(float s) {
    int v = __builtin_amdgcn_update_dpp(0, __builtin_bit_cast(int, s), CTRL, 0xF, 0xF, true);
    return s + __builtin_bit_cast(float, v);
}

__device__ __forceinline__ unsigned long long pack_val(float v) {
    return ((unsigned long long)__float_as_uint(v) << 32) | (unsigned long long)MAGIC;
}

// ================= fused producer/consumer kernel =================
__global__ __launch_bounds__(256, 8) void k_all(const float* __restrict__ x,
                                                const float* __restrict__ w,
                                                const float* __restrict__ wh_p,
                                                const float* __restrict__ bias,
                                                float* __restrict__ out,
                                                unsigned long long* __restrict__ uq,
                                                unsigned long long* __restrict__ pk) {
    const int tid  = threadIdx.x;
    const int lane = tid & 63;

    if (blockIdx.x < NDOT) {
        // ---------- producer: pure streaming dot (round-6 K1) ----------
        const int wave = ((int)blockIdx.x * 256 + tid) >> 6;   // 0..8191
        const int half = lane >> 5;
        const int hl   = lane & 31;
        const float4 wvec = *reinterpret_cast<const float4*>(w + hl * 4);
        const float  bs   = bias[0];
        const int row0 = wave * 16;        // 16 rows per wave
        float4 xv[8];
#pragma unroll
        for (int r = 0; r < 8; ++r) {
            const int row = row0 + r * 2 + half;
            xv[r] = *reinterpret_cast<const float4*>(x + (size_t)row * 512 + hl * 4);
        }
#pragma unroll
        for (int r = 0; r < 8; ++r) {
            float s = fmaf(xv[r].x, wvec.x, fmaf(xv[r].y, wvec.y,
                      fmaf(xv[r].z, wvec.z, xv[r].w * wvec.w)));
            s = dpp_add<0xB1>(s);    // xor1 (quad_perm)
            s = dpp_add<0x4E>(s);    // xor2 (quad_perm)
            s = dpp_add<0x141>(s);   // row_half_mirror
            s = dpp_add<0x140>(s);   // row_mirror
            s += __shfl_xor(s, 16, 64);
            if (hl == 0)
                __hip_atomic_store(&uq[row0 + r * 2 + half], pack_val(s + bs),
                                   __ATOMIC_RELAXED, __HIP_MEMORY_SCOPE_AGENT);
        }
        return;
    }

    // ---------- consumer: scan + decoupled lookback + write (round-6 K2) ----------
    __shared__ float wl[4];
    __shared__ float Sw[8];
    __shared__ float ex_s;
    const int wv   = tid >> 6;
    const int k    = (int)blockIdx.x - NDOT;   // chunk id 0..511
    const int base = k * CHUNK;

    // Poll this chunk's u values (value packed with flag: no fences needed).
    unsigned long long q = __hip_atomic_load(&uq[base + tid], __ATOMIC_RELAXED,
                                             __HIP_MEMORY_SCOPE_AGENT);
    while ((unsigned int)q != MAGIC) {
        __builtin_amdgcn_s_sleep(2);
        q = __hip_atomic_load(&uq[base + tid], __ATOMIC_RELAXED,
                              __HIP_MEMORY_SCOPE_AGENT);
    }
    float c = __uint_as_float((unsigned int)(q >> 32));

    const float a = wh_p[0];
    float fstep = a;
#pragma unroll
    for (int s = 1; s < 64; s <<= 1) {
        float prev = __shfl_up(c, (unsigned)s, 64);
        if (lane >= s) c = fmaf(prev, fstep, c);
        fstep *= fstep;
    }
    const float f64 = fstep;            // a^64
    float apw = a, bse = a;             // a^(lane+1)
#pragma unroll
    for (int b = 0; b < 6; ++b) { if (lane & (1 << b)) apw *= bse; bse *= bse; }

    if (lane == 63) wl[wv] = c;
    __syncthreads();
    if (wv > 0) {
        float seed = wl[0];
#pragma unroll
        for (int j = 1; j < 4; ++j) if (j < wv) seed = fmaf(seed, f64, wl[j]);
        c = fmaf(seed, apw, c);         // block-wide inclusive prefix
    }

    if (tid == CHUNK - 1)
        __hip_atomic_store(&pk[k], pack_val(c), __ATOMIC_RELAXED,
                           __HIP_MEMORY_SCOPE_AGENT);

    // Lookback: nw windows of 64 predecessors, distributed across 4 waves.
    const float Af = [&]{ float t2 = f64 * f64; return t2 * t2; }();   // a^256
    const int nw = (k + 63) >> 6;
    for (int wi = wv; wi < nw; wi += 4) {
        const int j0 = wi << 6;
        const int t  = min(64, k - j0);     // chunks in this window, 1..64
        float cj = 0.0f;
        if (lane < t) {
            unsigned long long qq = __hip_atomic_load(&pk[j0 + lane], __ATOMIC_RELAXED,
                                                      __HIP_MEMORY_SCOPE_AGENT);
            while ((unsigned int)qq != MAGIC) {
                __builtin_amdgcn_s_sleep(1);
                qq = __hip_atomic_load(&pk[j0 + lane], __ATOMIC_RELAXED,
                                       __HIP_MEMORY_SCOPE_AGENT);
            }
            cj = __uint_as_float((unsigned int)(qq >> 32));
        }
        float P = cj, ff = Af;              // weighted scan; lane t-1 = window sum
#pragma unroll
        for (int s = 1; s < 64; s <<= 1) {
            float prev = __shfl_up(P, (unsigned)s, 64);
            if (lane >= s) P = fmaf(prev, ff, P);
            ff *= ff;
        }
        if (lane == t - 1) Sw[wi] = P;
    }
    __syncthreads();

    if (tid == 0) {
        float ex = 0.0f;
        if (nw > 0) {
            float A64 = Af;
#pragma unroll
            for (int i = 0; i < 6; ++i) A64 *= A64;       // Af^64
            for (int wi = 0; wi < nw - 1; ++wi) ex = fmaf(ex, A64, Sw[wi]);
            const int tl = k - ((nw - 1) << 6);           // last-window length 1..64
            float At = 1.0f, bb = Af;
#pragma unroll
            for (int b = 0; b < 7; ++b) { if (tl & (1 << b)) At *= bb; bb *= bb; }
            ex = fmaf(ex, At, Sw[nw - 1]);
        }
        ex_s = ex;
    }
    __syncthreads();

    const float ex = ex_s;
    float pw = apw;
#pragma unroll
    for (int j = 0; j < 4; ++j) if (j < wv) pw *= f64;   // -> a^(tid+1)
    const float y = fmaf(pw, ex, c);
    out[base + tid] = y;
    if (k == NCHUNK - 1 && tid == CHUNK - 1) {           // y_h duplicated tail
        out[B_ROWS]     = y;
        out[B_ROWS + 1] = y;
    }
}

// ================= fallback: round-6 two-kernel path =================
__global__ __launch_bounds__(256) void k_dot(const float* __restrict__ x,
                                             const float* __restrict__ w,
                                             const float* __restrict__ bias,
                                             float* __restrict__ u) {
    const int gtid = blockIdx.x * 256 + threadIdx.x;
    const int wave = gtid >> 6;
    const int lane = threadIdx.x & 63;
    const int half = lane >> 5;
    const int hl   = lane & 31;
    const float4 wv = *reinterpret_cast<const float4*>(w + hl * 4);
    const float  bs = bias[0];
    const int row0 = wave * 16;
    float4 xv[8];
#pragma unroll
    for (int r = 0; r < 8; ++r)
        xv[r] = *reinterpret_cast<const float4*>(x + (size_t)(row0 + r * 2 + half) * 512 + hl * 4);
#pragma unroll
    for (int r = 0; r < 8; ++r) {
        float s = fmaf(xv[r].x, wv.x, fmaf(xv[r].y, wv.y,
                  fmaf(xv[r].z, wv.z, xv[r].w * wv.w)));
        s = dpp_add<0xB1>(s); s = dpp_add<0x4E>(s);
        s = dpp_add<0x141>(s); s = dpp_add<0x140>(s);
        s += __shfl_xor(s, 16, 64);
        if (hl == 0) u[row0 + r * 2 + half] = s + bs;
    }
}

__global__ __launch_bounds__(256) void k_scan_apply(const float* __restrict__ u,
                                                    const float* __restrict__ wh_p,
                                                    unsigned long long* __restrict__ pk,
                                                    float* __restrict__ out) {
    __shared__ float wl[4];
    __shared__ float Sw[8];
    __shared__ float ex_s;
    const int tid  = threadIdx.x;
    const int wv   = tid >> 6;
    const int lane = tid & 63;
    const int k    = blockIdx.x;
    const int base = k * CHUNK;

    const float a = wh_p[0];
    float c = u[base + tid];
    float fstep = a;
#pragma unroll
    for (int s = 1; s < 64; s <<= 1) {
        float prev = __shfl_up(c, (unsigned)s, 64);
        if (lane >= s) c = fmaf(prev, fstep, c);
        fstep *= fstep;
    }
    const float f64 = fstep;
    float apw = a, bse = a;
#pragma unroll
    for (int b = 0; b < 6; ++b) { if (lane & (1 << b)) apw *= bse; bse *= bse; }

    if (lane == 63) wl[wv] = c;
    __syncthreads();
    if (wv > 0) {
        float seed = wl[0];
#pragma unroll
        for (int j = 1; j < 4; ++j) if (j < wv) seed = fmaf(seed, f64, wl[j]);
        c = fmaf(seed, apw, c);
    }
    if (tid == CHUNK - 1)
        __hip_atomic_store(&pk[k], pack_val(c), __ATOMIC_RELAXED,
                           __HIP_MEMORY_SCOPE_AGENT);

    const float Af = [&]{ float t2 = f64 * f64; return t2 * t2; }();
    const int nw = (k + 63) >> 6;
    for (int wi = wv; wi < nw; wi += 4) {
        const int j0 = wi << 6;
        const int t  = min(64, k - j0);
        float cj = 0.0f;
        if (lane < t) {
            unsigned long long qq = __hip_atomic_load(&pk[j0 + lane], __ATOMIC_RELAXED,
                                                      __HIP_MEMORY_SCOPE_AGENT);
            while ((unsigned int)qq != MAGIC) {
                __builtin_amdgcn_s_sleep(1);
                qq = __hip_atomic_load(&pk[j0 + lane], __ATOMIC_RELAXED,
                                       __HIP_MEMORY_SCOPE_AGENT);
            }
            cj = __uint_as_float((unsigned int)(qq >> 32));
        }
        float P = cj, ff = Af;
#pragma unroll
        for (int s = 1; s < 64; s <<= 1) {
            float prev = __shfl_up(P, (unsigned)s, 64);
            if (lane >= s) P = fmaf(prev, ff, P);
            ff *= ff;
        }
        if (lane == t - 1) Sw[wi] = P;
    }
    __syncthreads();

    if (tid == 0) {
        float ex = 0.0f;
        if (nw > 0) {
            float A64 = Af;
#pragma unroll
            for (int i = 0; i < 6; ++i) A64 *= A64;
            for (int wi = 0; wi < nw - 1; ++wi) ex = fmaf(ex, A64, Sw[wi]);
            const int tl = k - ((nw - 1) << 6);
            float At = 1.0f, bb = Af;
#pragma unroll
            for (int b = 0; b < 7; ++b) { if (tl & (1 << b)) At *= bb; bb *= bb; }
            ex = fmaf(ex, At, Sw[nw - 1]);
        }
        ex_s = ex;
    }
    __syncthreads();

    const float ex = ex_s;
    float pw = apw;
#pragma unroll
    for (int j = 0; j < 4; ++j) if (j < wv) pw *= f64;
    const float y = fmaf(pw, ex, c);
    out[base + tid] = y;
    if (k == NCHUNK - 1 && tid == CHUNK - 1) {
        out[B_ROWS]     = y;
        out[B_ROWS + 1] = y;
    }
}

extern "C" void kernel_launch(void* const* d_in, const int* in_sizes, int n_in,
                              void* d_out, int out_size, void* d_ws, size_t ws_size,
                              hipStream_t stream) {
    const float* x    = (const float*)d_in[0];   // (131072, 4, 128) f32
    const float* w    = (const float*)d_in[1];   // (128, 1) f32
    const float* wh   = (const float*)d_in[2];   // (1, 1) f32
    const float* bias = (const float*)d_in[3];   // (1,) f32
    float* out = (float*)d_out;                  // 131074 f32

    const size_t need = (size_t)B_ROWS * 8 + (size_t)NCHUNK * 8;
    if (ws_size >= need) {
        unsigned long long* uq = (unsigned long long*)d_ws;      // B_ROWS qwords
        unsigned long long* pk = uq + B_ROWS;                    // NCHUNK qwords
        k_all<<<NDOT + NCHUNK, 256, 0, stream>>>(x, w, wh, bias, out, uq, pk);
    } else {
        float* u               = (float*)d_ws;                      // B_ROWS floats
        unsigned long long* pk = (unsigned long long*)(u + B_ROWS); // NCHUNK qwords
        k_dot<<<NDOT, 256, 0, stream>>>(x, w, bias, u);
        k_scan_apply<<<NCHUNK, 256, 0, stream>>>(u, wh, pk, out);
    }
}

// Round 10
// 18.919 us; speedup vs baseline: 1.1803x; 1.0694x over previous
//
#include <hip/hip_runtime.h>

// B=131072, S=4, D=128, H=1
//   u[b] = dot(x[b,0,:], w) + bias     (reads only first S-slice: 64 MB)
//   y[b] = u[b] + a*y[b-1],  a = weight_h[0,0]
// ONE dispatch, 2560 blocks: 2048 producer blocks stream the dot at full
// occupancy (NONTEMPORAL x loads: read-once stream, skip cache allocation)
// and publish u as {value,MAGIC} qwords (relaxed agent atomics — value
// travels with the flag, no fences); 512 consumer blocks poll their chunk's
// u, scan, decoupled-lookback over chunk aggregates, and write out.
// Deadlock-free for any dispatch order (producers never wait).

#define B_ROWS 131072
#define CHUNK  256
#define NCHUNK 512   // B_ROWS / CHUNK
#define NDOT   2048  // producer blocks
#define MAGIC  0x7C3A9E51u

typedef float f32x4 __attribute__((ext_vector_type(4)));

template <int CTRL>
__device__ __forceinline__ float dpp_add(float s) {
    int v = __builtin_amdgcn_update_dpp(0, __builtin_bit_cast(int, s), CTRL, 0xF, 0xF, true);
    return s + __builtin_bit_cast(float, v);
}

__device__ __forceinline__ unsigned long long pack_val(float v) {
    return ((unsigned long long)__float_as_uint(v) << 32) | (unsigned long long)MAGIC;
}

// ================= fused producer/consumer kernel =================
__global__ __launch_bounds__(256, 8) void k_all(const float* __restrict__ x,
                                                const float* __restrict__ w,
                                                const float* __restrict__ wh_p,
                                                const float* __restrict__ bias,
                                                float* __restrict__ out,
                                                unsigned long long* __restrict__ uq,
                                                unsigned long long* __restrict__ pk) {
    const int tid  = threadIdx.x;
    const int lane = tid & 63;

    if (blockIdx.x < NDOT) {
        // ---------- producer: pure streaming dot, nontemporal x loads ----------
        const int wave = ((int)blockIdx.x * 256 + tid) >> 6;   // 0..8191
        const int half = lane >> 5;
        const int hl   = lane & 31;
        const float4 wvec = *reinterpret_cast<const float4*>(w + hl * 4);
        const float  bs   = bias[0];
        const int row0 = wave * 16;        // 16 rows per wave
        f32x4 xv[8];
#pragma unroll
        for (int r = 0; r < 8; ++r) {
            const int row = row0 + r * 2 + half;
            xv[r] = __builtin_nontemporal_load(
                reinterpret_cast<const f32x4*>(x + (size_t)row * 512 + hl * 4));
        }
#pragma unroll
        for (int r = 0; r < 8; ++r) {
            float s = fmaf(xv[r].x, wvec.x, fmaf(xv[r].y, wvec.y,
                      fmaf(xv[r].z, wvec.z, xv[r].w * wvec.w)));
            s = dpp_add<0xB1>(s);    // xor1 (quad_perm)
            s = dpp_add<0x4E>(s);    // xor2 (quad_perm)
            s = dpp_add<0x141>(s);   // row_half_mirror
            s = dpp_add<0x140>(s);   // row_mirror
            s += __shfl_xor(s, 16, 64);
            if (hl == 0)
                __hip_atomic_store(&uq[row0 + r * 2 + half], pack_val(s + bs),
                                   __ATOMIC_RELAXED, __HIP_MEMORY_SCOPE_AGENT);
        }
        return;
    }

    // ---------- consumer: scan + decoupled lookback + write ----------
    __shared__ float wl[4];
    __shared__ float Sw[8];
    __shared__ float ex_s;
    const int wv   = tid >> 6;
    const int k    = (int)blockIdx.x - NDOT;   // chunk id 0..511
    const int base = k * CHUNK;

    // Poll this chunk's u values (value packed with flag: no fences needed).
    unsigned long long q = __hip_atomic_load(&uq[base + tid], __ATOMIC_RELAXED,
                                             __HIP_MEMORY_SCOPE_AGENT);
    while ((unsigned int)q != MAGIC) {
        __builtin_amdgcn_s_sleep(2);
        q = __hip_atomic_load(&uq[base + tid], __ATOMIC_RELAXED,
                              __HIP_MEMORY_SCOPE_AGENT);
    }
    float c = __uint_as_float((unsigned int)(q >> 32));

    const float a = wh_p[0];
    float fstep = a;
#pragma unroll
    for (int s = 1; s < 64; s <<= 1) {
        float prev = __shfl_up(c, (unsigned)s, 64);
        if (lane >= s) c = fmaf(prev, fstep, c);
        fstep *= fstep;
    }
    const float f64 = fstep;            // a^64
    float apw = a, bse = a;             // a^(lane+1)
#pragma unroll
    for (int b = 0; b < 6; ++b) { if (lane & (1 << b)) apw *= bse; bse *= bse; }

    if (lane == 63) wl[wv] = c;
    __syncthreads();
    if (wv > 0) {
        float seed = wl[0];
#pragma unroll
        for (int j = 1; j < 4; ++j) if (j < wv) seed = fmaf(seed, f64, wl[j]);
        c = fmaf(seed, apw, c);         // block-wide inclusive prefix
    }

    if (tid == CHUNK - 1)
        __hip_atomic_store(&pk[k], pack_val(c), __ATOMIC_RELAXED,
                           __HIP_MEMORY_SCOPE_AGENT);

    // Lookback: nw windows of 64 predecessors, distributed across 4 waves.
    const float Af = [&]{ float t2 = f64 * f64; return t2 * t2; }();   // a^256
    const int nw = (k + 63) >> 6;
    for (int wi = wv; wi < nw; wi += 4) {
        const int j0 = wi << 6;
        const int t  = min(64, k - j0);     // chunks in this window, 1..64
        float cj = 0.0f;
        if (lane < t) {
            unsigned long long qq = __hip_atomic_load(&pk[j0 + lane], __ATOMIC_RELAXED,
                                                      __HIP_MEMORY_SCOPE_AGENT);
            while ((unsigned int)qq != MAGIC) {
                __builtin_amdgcn_s_sleep(1);
                qq = __hip_atomic_load(&pk[j0 + lane], __ATOMIC_RELAXED,
                                       __HIP_MEMORY_SCOPE_AGENT);
            }
            cj = __uint_as_float((unsigned int)(qq >> 32));
        }
        float P = cj, ff = Af;              // weighted scan; lane t-1 = window sum
#pragma unroll
        for (int s = 1; s < 64; s <<= 1) {
            float prev = __shfl_up(P, (unsigned)s, 64);
            if (lane >= s) P = fmaf(prev, ff, P);
            ff *= ff;
        }
        if (lane == t - 1) Sw[wi] = P;
    }
    __syncthreads();

    if (tid == 0) {
        float ex = 0.0f;
        if (nw > 0) {
            float A64 = Af;
#pragma unroll
            for (int i = 0; i < 6; ++i) A64 *= A64;       // Af^64
            for (int wi = 0; wi < nw - 1; ++wi) ex = fmaf(ex, A64, Sw[wi]);
            const int tl = k - ((nw - 1) << 6);           // last-window length 1..64
            float At = 1.0f, bb = Af;
#pragma unroll
            for (int b = 0; b < 7; ++b) { if (tl & (1 << b)) At *= bb; bb *= bb; }
            ex = fmaf(ex, At, Sw[nw - 1]);
        }
        ex_s = ex;
    }
    __syncthreads();

    const float ex = ex_s;
    float pw = apw;
#pragma unroll
    for (int j = 0; j < 4; ++j) if (j < wv) pw *= f64;   // -> a^(tid+1)
    const float y = fmaf(pw, ex, c);
    out[base + tid] = y;
    if (k == NCHUNK - 1 && tid == CHUNK - 1) {           // y_h duplicated tail
        out[B_ROWS]     = y;
        out[B_ROWS + 1] = y;
    }
}

// ================= fallback: two-kernel path (small ws) =================
__global__ __launch_bounds__(256) void k_dot(const float* __restrict__ x,
                                             const float* __restrict__ w,
                                             const float* __restrict__ bias,
                                             float* __restrict__ u) {
    const int gtid = blockIdx.x * 256 + threadIdx.x;
    const int wave = gtid >> 6;
    const int lane = threadIdx.x & 63;
    const int half = lane >> 5;
    const int hl   = lane & 31;
    const float4 wv = *reinterpret_cast<const float4*>(w + hl * 4);
    const float  bs = bias[0];
    const int row0 = wave * 16;
    f32x4 xv[8];
#pragma unroll
    for (int r = 0; r < 8; ++r)
        xv[r] = __builtin_nontemporal_load(
            reinterpret_cast<const f32x4*>(x + (size_t)(row0 + r * 2 + half) * 512 + hl * 4));
#pragma unroll
    for (int r = 0; r < 8; ++r) {
        float s = fmaf(xv[r].x, wv.x, fmaf(xv[r].y, wv.y,
                  fmaf(xv[r].z, wv.z, xv[r].w * wv.w)));
        s = dpp_add<0xB1>(s); s = dpp_add<0x4E>(s);
        s = dpp_add<0x141>(s); s = dpp_add<0x140>(s);
        s += __shfl_xor(s, 16, 64);
        if (hl == 0) u[row0 + r * 2 + half] = s + bs;
    }
}

__global__ __launch_bounds__(256) void k_scan_apply(const float* __restrict__ u,
                                                    const float* __restrict__ wh_p,
                                                    unsigned long long* __restrict__ pk,
                                                    float* __restrict__ out) {
    __shared__ float wl[4];
    __shared__ float Sw[8];
    __shared__ float ex_s;
    const int tid  = threadIdx.x;
    const int wv   = tid >> 6;
    const int lane = tid & 63;
    const int k    = blockIdx.x;
    const int base = k * CHUNK;

    const float a = wh_p[0];
    float c = u[base + tid];
    float fstep = a;
#pragma unroll
    for (int s = 1; s < 64; s <<= 1) {
        float prev = __shfl_up(c, (unsigned)s, 64);
        if (lane >= s) c = fmaf(prev, fstep, c);
        fstep *= fstep;
    }
    const float f64 = fstep;
    float apw = a, bse = a;
#pragma unroll
    for (int b = 0; b < 6; ++b) { if (lane & (1 << b)) apw *= bse; bse *= bse; }

    if (lane == 63) wl[wv] = c;
    __syncthreads();
    if (wv > 0) {
        float seed = wl[0];
#pragma unroll
        for (int j = 1; j < 4; ++j) if (j < wv) seed = fmaf(seed, f64, wl[j]);
        c = fmaf(seed, apw, c);
    }
    if (tid == CHUNK - 1)
        __hip_atomic_store(&pk[k], pack_val(c), __ATOMIC_RELAXED,
                           __HIP_MEMORY_SCOPE_AGENT);

    const float Af = [&]{ float t2 = f64 * f64; return t2 * t2; }();
    const int nw = (k + 63) >> 6;
    for (int wi = wv; wi < nw; wi += 4) {
        const int j0 = wi << 6;
        const int t  = min(64, k - j0);
        float cj = 0.0f;
        if (lane < t) {
            unsigned long long qq = __hip_atomic_load(&pk[j0 + lane], __ATOMIC_RELAXED,
                                                      __HIP_MEMORY_SCOPE_AGENT);
            while ((unsigned int)qq != MAGIC) {
                __builtin_amdgcn_s_sleep(1);
                qq = __hip_atomic_load(&pk[j0 + lane], __ATOMIC_RELAXED,
                                       __HIP_MEMORY_SCOPE_AGENT);
            }
            cj = __uint_as_float((unsigned int)(qq >> 32));
        }
        float P = cj, ff = Af;
#pragma unroll
        for (int s = 1; s < 64; s <<= 1) {
            float prev = __shfl_up(P, (unsigned)s, 64);
            if (lane >= s) P = fmaf(prev, ff, P);
            ff *= ff;
        }
        if (lane == t - 1) Sw[wi] = P;
    }
    __syncthreads();

    if (tid == 0) {
        float ex = 0.0f;
        if (nw > 0) {
            float A64 = Af;
#pragma unroll
            for (int i = 0; i < 6; ++i) A64 *= A64;
            for (int wi = 0; wi < nw - 1; ++wi) ex = fmaf(ex, A64, Sw[wi]);
            const int tl = k - ((nw - 1) << 6);
            float At = 1.0f, bb = Af;
#pragma unroll
            for (int b = 0; b < 7; ++b) { if (tl & (1 << b)) At *= bb; bb *= bb; }
            ex = fmaf(ex, At, Sw[nw - 1]);
        }
        ex_s = ex;
    }
    __syncthreads();

    const float ex = ex_s;
    float pw = apw;
#pragma unroll
    for (int j = 0; j < 4; ++j) if (j < wv) pw *= f64;
    const float y = fmaf(pw, ex, c);
    out[base + tid] = y;
    if (k == NCHUNK - 1 && tid == CHUNK - 1) {
        out[B_ROWS]     = y;
        out[B_ROWS + 1] = y;
    }
}

extern "C" void kernel_launch(void* const* d_in, const int* in_sizes, int n_in,
                              void* d_out, int out_size, void* d_ws, size_t ws_size,
                              hipStream_t stream) {
    const float* x    = (const float*)d_in[0];   // (131072, 4, 128) f32
    const float* w    = (const float*)d_in[1];   // (128, 1) f32
    const float* wh   = (const float*)d_in[2];   // (1, 1) f32
    const float* bias = (const float*)d_in[3];   // (1,) f32
    float* out = (float*)d_out;                  // 131074 f32

    const size_t need = (size_t)B_ROWS * 8 + (size_t)NCHUNK * 8;
    if (ws_size >= need) {
        unsigned long long* uq = (unsigned long long*)d_ws;      // B_ROWS qwords
        unsigned long long* pk = uq + B_ROWS;                    // NCHUNK qwords
        k_all<<<NDOT + NCHUNK, 256, 0, stream>>>(x, w, wh, bias, out, uq, pk);
    } else {
        float* u               = (float*)d_ws;                      // B_ROWS floats
        unsigned long long* pk = (unsigned long long*)(u + B_ROWS); // NCHUNK qwords
        k_dot<<<NDOT, 256, 0, stream>>>(x, w, bias, u);
        k_scan_apply<<<NCHUNK, 256, 0, stream>>>(u, wh, pk, out);
    }
}